// Round 8
// baseline (356.234 us; speedup 1.0000x reference)
//
#include <hip/hip_runtime.h>
#include <hip/hip_bf16.h>

#define BATCH   2
#define SEQ     4096
#define DMODEL  512
#define DINNER  1024
#define DSTATE  64
#define NHEADS  16
#define HEADDIM 64
#define CONVDIM 1152
#define NPROJ   2192
#define MROWS   (BATCH*SEQ)   // 8192
#define QCH     64
#define NCHUNK  (SEQ/QCH)     // 64 chunks per batch

typedef short bf16x8 __attribute__((ext_vector_type(8)));
typedef float f32x4  __attribute__((ext_vector_type(4)));
using bf16 = __hip_bfloat16;
typedef unsigned short ushort_t;
typedef unsigned int   uint_t;

__device__ __forceinline__ float sigmoidf_(float x) { return 1.f / (1.f + __expf(-x)); }
__device__ __forceinline__ float bf2f(ushort_t u) { return __uint_as_float((uint_t)u << 16); }
__device__ __forceinline__ ushort_t f2bfu(float f) {
    bf16 h = __float2bfloat16(f);
    return *(ushort_t*)&h;
}
__device__ __forceinline__ void bf8_to_f(const ushort_t* __restrict__ p, float* __restrict__ f) {
    uint4 u = *(const uint4*)p;
    f[0] = __uint_as_float((u.x & 0xFFFFu) << 16);
    f[1] = __uint_as_float(u.x & 0xFFFF0000u);
    f[2] = __uint_as_float((u.y & 0xFFFFu) << 16);
    f[3] = __uint_as_float(u.y & 0xFFFF0000u);
    f[4] = __uint_as_float((u.z & 0xFFFFu) << 16);
    f[5] = __uint_as_float(u.z & 0xFFFF0000u);
    f[6] = __uint_as_float((u.w & 0xFFFFu) << 16);
    f[7] = __uint_as_float(u.w & 0xFFFF0000u);
}
__device__ __forceinline__ uint4 f8_to_bf(const float* __restrict__ f) {
    union { ushort_t s[8]; uint4 u; } r;
#pragma unroll
    for (int i = 0; i < 8; i++) r.s[i] = f2bfu(f[i]);
    return r.u;
}

// ---------------------------------------------------------------- fp32 -> bf16 cast (8/thread)
__global__ void cast_f32_bf16_k(const float* __restrict__ in, ushort_t* __restrict__ out, int n8)
{
    int i = blockIdx.x * 256 + threadIdx.x;
    if (i >= n8) return;
    float f[8];
    *(float4*)(f + 0) = ((const float4*)in)[i * 2 + 0];
    *(float4*)(f + 4) = ((const float4*)in)[i * 2 + 1];
    ((uint4*)out)[i] = f8_to_bf(f);
}

// ---------------------------------------------------------------- transpose fp32 in[R][C] -> bf16 out[C][R]
__global__ void transpose_f32_bf16_k(const float* __restrict__ in, ushort_t* __restrict__ out,
                                     int R, int C)
{
    __shared__ __align__(16) ushort_t tile[32][33];
    int c0 = blockIdx.x * 32, r0 = blockIdx.y * 32;
    int tx = threadIdx.x, ty = threadIdx.y;
#pragma unroll
    for (int i = 0; i < 32; i += 8) {
        int r = r0 + ty + i, c = c0 + tx;
        tile[ty + i][tx] = (r < R && c < C) ? f2bfu(in[(size_t)r * C + c]) : (ushort_t)0;
    }
    __syncthreads();
#pragma unroll
    for (int i = 0; i < 32; i += 8) {
        int orow = c0 + ty + i, ocol = r0 + tx;
        if (orow < C && ocol < R) out[(size_t)orow * R + ocol] = tile[tx][ty + i];
    }
}

// ---------------------------------------------------------------- GEMM (bf16 MFMA), both operands bf16 k-contig
// C[M][N] = A[M][K] @ Bt[N][K]^T.  MODE 0: split epilogue (z/xpx/xpbc/dt).  MODE 1: fp32 out.
template<int MODE>
__global__ __launch_bounds__(256, 2)
void gemm_k(const ushort_t* __restrict__ A, const ushort_t* __restrict__ Bt,
            ushort_t* __restrict__ zbuf, ushort_t* __restrict__ xpx,
            ushort_t* __restrict__ xpbc, float* __restrict__ dtv,
            float* __restrict__ dalog, const float* __restrict__ dt_b,
            const float* __restrict__ A_log, float* __restrict__ outf,
            int M, int N, int K)
{
    constexpr int SA = 72;
    __shared__ __align__(16) ushort_t As[128 * SA];
    __shared__ __align__(16) ushort_t Bs[128 * SA];

    const int tid  = threadIdx.x;
    const int wave = tid >> 6, lane = tid & 63;
    const int quad = lane >> 4, l16 = lane & 15;
    const int wm = (wave >> 1) * 64, wn = (wave & 1) * 64;
    const int m0 = blockIdx.y * 128, n0 = blockIdx.x * 128;

    const int srow = tid >> 1, scol = (tid & 1) * 32;  // 2 threads/row, 32 bf16 (64B) each
    const int  gn     = n0 + srow;
    const bool bvalid = (gn < N);

    f32x4 acc[4][4];
#pragma unroll
    for (int i = 0; i < 4; i++)
#pragma unroll
        for (int j = 0; j < 4; j++) acc[i][j] = (f32x4){0.f, 0.f, 0.f, 0.f};

    for (int k0 = 0; k0 < K; k0 += 64) {
        uint4 av[4], bv[4];
        const uint4* ap = (const uint4*)(A + (size_t)(m0 + srow) * K + k0 + scol);
#pragma unroll
        for (int j = 0; j < 4; j++) av[j] = ap[j];
        if (bvalid) {
            const uint4* bp = (const uint4*)(Bt + (size_t)gn * K + k0 + scol);
#pragma unroll
            for (int j = 0; j < 4; j++) bv[j] = bp[j];
        } else {
#pragma unroll
            for (int j = 0; j < 4; j++) bv[j] = (uint4){0u, 0u, 0u, 0u};
        }
        __syncthreads();
        {
            uint4* asw = (uint4*)(&As[srow * SA + scol]);
            uint4* bsw = (uint4*)(&Bs[srow * SA + scol]);
#pragma unroll
            for (int j = 0; j < 4; j++) { asw[j] = av[j]; bsw[j] = bv[j]; }
        }
        __syncthreads();
#pragma unroll
        for (int kk = 0; kk < 64; kk += 32) {
            bf16x8 af[4], bfr[4];
#pragma unroll
            for (int i = 0; i < 4; i++)
                af[i] = *(const bf16x8*)(&As[(wm + i * 16 + l16) * SA + kk + quad * 8]);
#pragma unroll
            for (int j = 0; j < 4; j++)
                bfr[j] = *(const bf16x8*)(&Bs[(wn + j * 16 + l16) * SA + kk + quad * 8]);
#pragma unroll
            for (int i = 0; i < 4; i++)
#pragma unroll
                for (int j = 0; j < 4; j++)
                    acc[i][j] = __builtin_amdgcn_mfma_f32_16x16x32_bf16(af[i], bfr[j], acc[i][j], 0, 0, 0);
        }
    }
    // ---- epilogue: C/D layout col=lane&15, row=quad*4+reg (m89/m91 verified) ----
#pragma unroll
    for (int i = 0; i < 4; i++) {
#pragma unroll
        for (int j = 0; j < 4; j++) {
            int col = n0 + wn + j * 16 + l16;
            int rowb = m0 + wm + i * 16 + quad * 4;
#pragma unroll
            for (int r = 0; r < 4; r++) {
                float v = acc[i][j][r];
                size_t g = (size_t)(rowb + r);
                if (MODE == 1) {
                    outf[g * N + col] = v;
                } else {
                    if (n0 < 1024)        zbuf[g * 1024 + col] = f2bfu(v);
                    else if (n0 < 2048)   xpx [g * 1024 + (col - 1024)] = f2bfu(v);
                    else if (n0 == 2048)  xpbc[g * 128  + (col - 2048)] = f2bfu(v);
                    else if (col < N) {
                        int hh = col - 2176;
                        float raw = v + dt_b[hh];
                        float sp  = (raw > 20.f) ? raw : log1pf(__expf(raw));
                        dtv  [g * NHEADS + hh] = sp;
                        dalog[g * NHEADS + hh] = -__expf(A_log[hh]) * sp;
                    }
                }
            }
        }
    }
}

// ---------------------------------------------------------------- per-chunk state outer product (MFMA) — unchanged
// statesT[c][b][h][p][n] = sum_t xs[t][p] * (wc_t * B[t][n])    (bf16 out, TRANSPOSED [p][n])
__global__ __launch_bounds__(256, 2)
void chunk_state_k(const ushort_t* __restrict__ xpx, const ushort_t* __restrict__ xpbc,
                   const float* __restrict__ dtv, const float* __restrict__ dalog,
                   const float* __restrict__ cw, const float* __restrict__ cb,
                   ushort_t* __restrict__ statesT, float* __restrict__ cdecay)
{
    const int c = blockIdx.x, h = blockIdx.y, b = blockIdx.z;
    __shared__ __align__(16) ushort_t xsT[64 * 72];   // [p][t]  t-contig
    __shared__ __align__(16) ushort_t BwT[64 * 72];   // [n][t]  t-contig, weighted by wc[t]
    __shared__ float wc[64];
    const int tid = threadIdx.x;
    const int ts = tid >> 2, q4 = (tid & 3) * 16;
    const int l = c * QCH + ts;
    if (tid < 64) {
        size_t gl = ((size_t)b * SEQ + c * QCH + tid) * NHEADS + h;
        float v = dalog[gl];
#pragma unroll
        for (int off = 1; off < 64; off <<= 1) {
            float u = __shfl_up(v, off, 64);
            if (tid >= off) v += u;
        }
        float tot = __shfl(v, 63, 64);
        wc[tid] = __expf(tot - v) * dtv[gl];
        if (tid == 63) cdecay[(c * BATCH + b) * NHEADS + h] = __expf(tot);
    }
    __syncthreads();
    {
        const int ch0 = h * HEADDIM + q4;
        float a16[16];
#pragma unroll
        for (int i = 0; i < 16; i++) a16[i] = cb[ch0 + i];
#pragma unroll
        for (int j = 0; j < 4; j++) {
            int ll = l - 3 + j;
            if (ll >= 0) {
                float xv[16];
                const ushort_t* rp = xpx + ((size_t)b * SEQ + ll) * 1024 + ch0;
                bf8_to_f(rp, xv); bf8_to_f(rp + 8, xv + 8);
#pragma unroll
                for (int i = 0; i < 16; i++) a16[i] += cw[(ch0 + i) * 4 + j] * xv[i];
            }
        }
#pragma unroll
        for (int i = 0; i < 16; i++) { float v = a16[i]; xsT[(q4 + i) * 72 + ts] = f2bfu(v * sigmoidf_(v)); }
    }
    {
        float b16[16];
#pragma unroll
        for (int i = 0; i < 16; i++) b16[i] = cb[1024 + q4 + i];
#pragma unroll
        for (int j = 0; j < 4; j++) {
            int ll = l - 3 + j;
            if (ll >= 0) {
                float bv[16];
                const ushort_t* rp = xpbc + ((size_t)b * SEQ + ll) * 128;
                bf8_to_f(rp + q4, bv); bf8_to_f(rp + q4 + 8, bv + 8);
#pragma unroll
                for (int i = 0; i < 16; i++) b16[i] += cw[(1024 + q4 + i) * 4 + j] * bv[i];
            }
        }
        const float wt = wc[ts];
#pragma unroll
        for (int i = 0; i < 16; i++) { float v = b16[i]; BwT[(q4 + i) * 72 + ts] = f2bfu(v * sigmoidf_(v) * wt); }
    }
    __syncthreads();
    const int wave = tid >> 6, lane = tid & 63;
    const int quad = lane >> 4, l16 = lane & 15;
    f32x4 acc[4];
#pragma unroll
    for (int j = 0; j < 4; j++) acc[j] = (f32x4){0.f, 0.f, 0.f, 0.f};
#pragma unroll
    for (int kk = 0; kk < 64; kk += 32) {
        bf16x8 af = *(const bf16x8*)(&xsT[(wave * 16 + l16) * 72 + kk + quad * 8]);
#pragma unroll
        for (int j = 0; j < 4; j++) {
            bf16x8 bf_ = *(const bf16x8*)(&BwT[(j * 16 + l16) * 72 + kk + quad * 8]);
            acc[j] = __builtin_amdgcn_mfma_f32_16x16x32_bf16(af, bf_, acc[j], 0, 0, 0);
        }
    }
    ushort_t* base = statesT + ((size_t)(c * BATCH + b) * NHEADS + h) * (HEADDIM * DSTATE);
#pragma unroll
    for (int j = 0; j < 4; j++)
#pragma unroll
        for (int r = 0; r < 4; r++)
            base[(wave * 16 + quad * 4 + r) * 64 + j * 16 + l16] = f2bfu(acc[j][r]);
}

// ---------------------------------------------------------------- sequential chunk combine — unchanged
__global__ void scan_combine_k(ushort_t* __restrict__ states, const float* __restrict__ cdecay)
{
    const int blk = blockIdx.x;           // 128 = 2*16*4
    const int quarter = blk & 3;
    const int h = (blk >> 2) & 15;
    const int b = blk >> 6;
    const int tid = threadIdx.x;
    __shared__ float dec[64];
    if (tid < 64) dec[tid] = cdecay[(tid * BATCH + b) * NHEADS + h];
    __syncthreads();
    const size_t cstride = (size_t)BATCH * NHEADS * HEADDIM * DSTATE;  // elements
    ushort_t* base = states + ((size_t)b * NHEADS + h) * (HEADDIM * DSTATE) + quarter * 1024 + tid * 4;
    float sx = 0.f, sy = 0.f, sz = 0.f, sw = 0.f;
    uint2 pre[4];
#pragma unroll
    for (int j = 0; j < 4; j++) pre[j] = *(const uint2*)(base + j * cstride);
    for (int c = 0; c < NCHUNK; c++) {
        uint2 Sc = pre[c & 3];
        if (c + 4 < NCHUNK) pre[c & 3] = *(const uint2*)(base + (size_t)(c + 4) * cstride);
        float d = dec[c];
        uint2 o;
        o.x = (uint_t)f2bfu(sx) | ((uint_t)f2bfu(sy) << 16);
        o.y = (uint_t)f2bfu(sz) | ((uint_t)f2bfu(sw) << 16);
        *(uint2*)(base + (size_t)c * cstride) = o;
        sx = d * sx + __uint_as_float((Sc.x & 0xFFFFu) << 16);
        sy = d * sy + __uint_as_float(Sc.x & 0xFFFF0000u);
        sz = d * sz + __uint_as_float((Sc.y & 0xFFFFu) << 16);
        sw = d * sw + __uint_as_float(Sc.y & 0xFFFF0000u);
    }
}

// ---------------------------------------------------------------- per-chunk y (MFMA) — unchanged
__global__ __launch_bounds__(256, 2)
void chunk_y_k(const ushort_t* __restrict__ xpx, const ushort_t* __restrict__ xpbc,
               ushort_t* zio,
               const float* __restrict__ dtv, const float* __restrict__ dalog,
               const ushort_t* __restrict__ statesT, const float* __restrict__ cw,
               const float* __restrict__ cb, const float* __restrict__ Dp)
{
    const int c = blockIdx.x, h = blockIdx.y, b = blockIdx.z;
    __shared__ __align__(16) ushort_t CLb [64 * 72];  // C[t][n] n-contig
    __shared__ __align__(16) ushort_t BLb [64 * 72];  // B[s][n] n-contig -> ybuf[t][p]
    __shared__ __align__(16) ushort_t xsT [64 * 72];  // xs^T [p][t] t-contig
    __shared__ __align__(16) ushort_t attL[64 * 72];  // att[t][s] s-contig
    __shared__ float cum[64], wdt[64];
    const int tid = threadIdx.x;
    const int ts = tid >> 2, q4 = (tid & 3) * 16;
    const int l = c * QCH + ts;
    const float Dh = Dp[h];
    {
        const int ch0 = h * HEADDIM + q4;
        float a16[16];
#pragma unroll
        for (int i = 0; i < 16; i++) a16[i] = cb[ch0 + i];
#pragma unroll
        for (int j = 0; j < 4; j++) {
            int ll = l - 3 + j;
            if (ll >= 0) {
                float xv[16];
                const ushort_t* rp = xpx + ((size_t)b * SEQ + ll) * 1024 + ch0;
                bf8_to_f(rp, xv); bf8_to_f(rp + 8, xv + 8);
#pragma unroll
                for (int i = 0; i < 16; i++) a16[i] += cw[(ch0 + i) * 4 + j] * xv[i];
            }
        }
#pragma unroll
        for (int i = 0; i < 16; i++) { float v = a16[i]; xsT[(q4 + i) * 72 + ts] = f2bfu(v * sigmoidf_(v)); }
    }
    {
        float b16[16], c16[16];
#pragma unroll
        for (int i = 0; i < 16; i++) { b16[i] = cb[1024 + q4 + i]; c16[i] = cb[1088 + q4 + i]; }
#pragma unroll
        for (int j = 0; j < 4; j++) {
            int ll = l - 3 + j;
            if (ll >= 0) {
                const ushort_t* rp = xpbc + ((size_t)b * SEQ + ll) * 128;
                float bv[16], cv[16];
                bf8_to_f(rp + q4, bv);      bf8_to_f(rp + q4 + 8, bv + 8);
                bf8_to_f(rp + 64 + q4, cv); bf8_to_f(rp + 64 + q4 + 8, cv + 8);
#pragma unroll
                for (int i = 0; i < 16; i++) {
                    b16[i] += cw[(1024 + q4 + i) * 4 + j] * bv[i];
                    c16[i] += cw[(1088 + q4 + i) * 4 + j] * cv[i];
                }
            }
        }
        float bs[16], cs[16];
#pragma unroll
        for (int i = 0; i < 16; i++) {
            float v = b16[i]; bs[i] = v * sigmoidf_(v);
            float u = c16[i]; cs[i] = u * sigmoidf_(u);
        }
        *(uint4*)&BLb[ts * 72 + q4]     = f8_to_bf(bs);
        *(uint4*)&BLb[ts * 72 + q4 + 8] = f8_to_bf(bs + 8);
        *(uint4*)&CLb[ts * 72 + q4]     = f8_to_bf(cs);
        *(uint4*)&CLb[ts * 72 + q4 + 8] = f8_to_bf(cs + 8);
    }
    if (tid < 64) {
        size_t gl = ((size_t)b * SEQ + c * QCH + tid) * NHEADS + h;
        float v = dalog[gl];
#pragma unroll
        for (int off = 1; off < 64; off <<= 1) {
            float u = __shfl_up(v, off, 64);
            if (tid >= off) v += u;
        }
        cum[tid] = v;
        wdt[tid] = dtv[gl];
    }
    __syncthreads();
    const int wave = tid >> 6, lane = tid & 63;
    const int quad = lane >> 4, l16 = lane & 15;
    {
        f32x4 sacc[4];
#pragma unroll
        for (int j = 0; j < 4; j++) sacc[j] = (f32x4){0.f, 0.f, 0.f, 0.f};
#pragma unroll
        for (int kk = 0; kk < 64; kk += 32) {
            bf16x8 af = *(const bf16x8*)(&CLb[(wave * 16 + l16) * 72 + kk + quad * 8]);
#pragma unroll
            for (int j = 0; j < 4; j++) {
                bf16x8 bf_ = *(const bf16x8*)(&BLb[(j * 16 + l16) * 72 + kk + quad * 8]);
                sacc[j] = __builtin_amdgcn_mfma_f32_16x16x32_bf16(af, bf_, sacc[j], 0, 0, 0);
            }
        }
#pragma unroll
        for (int r = 0; r < 4; r++) {
            const int t = wave * 16 + quad * 4 + r;
            const float ct = cum[t];
#pragma unroll
            for (int j = 0; j < 4; j++) {
                const int s = j * 16 + l16;
                float a = (s <= t) ? sacc[j][r] * __expf(ct - cum[s]) * wdt[s] : 0.f;
                attL[t * 72 + s] = f2bfu(a);
            }
        }
    }
    __syncthreads();
    {
        f32x4 accY[4], accI[4];
#pragma unroll
        for (int j = 0; j < 4; j++) { accY[j] = (f32x4){0.f, 0.f, 0.f, 0.f}; accI[j] = (f32x4){0.f, 0.f, 0.f, 0.f}; }
        const ushort_t* spg = statesT + ((size_t)(c * BATCH + b) * NHEADS + h) * (HEADDIM * DSTATE);
#pragma unroll
        for (int kk = 0; kk < 64; kk += 32) {
            bf16x8 a2 = *(const bf16x8*)(&attL[(wave * 16 + l16) * 72 + kk + quad * 8]);
            bf16x8 a3 = *(const bf16x8*)(&CLb [(wave * 16 + l16) * 72 + kk + quad * 8]);
#pragma unroll
            for (int j = 0; j < 4; j++) {
                bf16x8 b2 = *(const bf16x8*)(&xsT[(j * 16 + l16) * 72 + kk + quad * 8]);
                accY[j] = __builtin_amdgcn_mfma_f32_16x16x32_bf16(a2, b2, accY[j], 0, 0, 0);
                bf16x8 b3 = *(const bf16x8*)(spg + (j * 16 + l16) * 64 + kk + quad * 8);
                accI[j] = __builtin_amdgcn_mfma_f32_16x16x32_bf16(a3, b3, accI[j], 0, 0, 0);
            }
        }
#pragma unroll
        for (int r = 0; r < 4; r++) {
            const int t = wave * 16 + quad * 4 + r;
            const float et = __expf(cum[t]);
#pragma unroll
            for (int j = 0; j < 4; j++) {
                const int p = j * 16 + l16;
                float xv = bf2f(xsT[p * 72 + t]);
                float y = accY[j][r] + et * accI[j][r] + Dh * xv;
                BLb[t * 72 + p] = f2bfu(y);
            }
        }
    }
    __syncthreads();
    {
        ushort_t* zrow = zio + ((size_t)b * SEQ + l) * DINNER + h * HEADDIM + q4;
        float zv[16], yv[16], o[16];
        bf8_to_f(zrow, zv); bf8_to_f(zrow + 8, zv + 8);
        bf8_to_f(&BLb[ts * 72 + q4], yv); bf8_to_f(&BLb[ts * 72 + q4 + 8], yv + 8);
#pragma unroll
        for (int j = 0; j < 16; j++) {
            float z = zv[j];
            o[j] = yv[j] * z * sigmoidf_(z);
        }
        *(uint4*)(zrow)     = f8_to_bf(o);
        *(uint4*)(zrow + 8) = f8_to_bf(o + 8);
    }
}

// ---------------------------------------------------------------- RMSNorm (in place, bf16) — unchanged
__global__ void rmsnorm_k(ushort_t* yio, const float* __restrict__ nw)
{
    const int row = blockIdx.x, tid = threadIdx.x;
    uint2 u = *(const uint2*)(yio + (size_t)row * DINNER + tid * 4);
    float v0 = __uint_as_float((u.x & 0xFFFFu) << 16);
    float v1 = __uint_as_float(u.x & 0xFFFF0000u);
    float v2 = __uint_as_float((u.y & 0xFFFFu) << 16);
    float v3 = __uint_as_float(u.y & 0xFFFF0000u);
    float ss = v0 * v0 + v1 * v1 + v2 * v2 + v3 * v3;
#pragma unroll
    for (int off = 32; off >= 1; off >>= 1) ss += __shfl_xor(ss, off, 64);
    __shared__ float part[4];
    const int wave = tid >> 6;
    if ((tid & 63) == 0) part[wave] = ss;
    __syncthreads();
    float tot = part[0] + part[1] + part[2] + part[3];
    float scale = rsqrtf(tot * (1.f / DINNER) + 1e-5f);
    uint2 o;
    o.x = (uint_t)f2bfu(v0 * scale * nw[tid * 4 + 0]) | ((uint_t)f2bfu(v1 * scale * nw[tid * 4 + 1]) << 16);
    o.y = (uint_t)f2bfu(v2 * scale * nw[tid * 4 + 2]) | ((uint_t)f2bfu(v3 * scale * nw[tid * 4 + 3]) << 16);
    *(uint2*)(yio + (size_t)row * DINNER + tid * 4) = o;
}

// ---------------------------------------------------------------- launch
extern "C" void kernel_launch(void* const* d_in, const int* in_sizes, int n_in,
                              void* d_out, int out_size, void* d_ws, size_t ws_size,
                              hipStream_t stream)
{
    const float* x      = (const float*)d_in[0];
    const float* W_in   = (const float*)d_in[1];
    const float* conv_w = (const float*)d_in[2];
    const float* conv_b = (const float*)d_in[3];
    const float* dt_b   = (const float*)d_in[4];
    const float* A_log  = (const float*)d_in[5];
    const float* Dp     = (const float*)d_in[6];
    const float* nw     = (const float*)d_in[7];
    const float* W_out  = (const float*)d_in[8];
    float* out = (float*)d_out;                    // (2,4096,512) fp32

    // ---- workspace (48 MiB high-water, unchanged) ----
    char* w = (char*)d_ws;
    ushort_t* zbuf    = (ushort_t*)(w);                 // [0,16M): z -> y -> yn (in place)
    ushort_t* xpx     = (ushort_t*)(w + 16777216);      // [16M,32M): pre-conv xBC x-part
    ushort_t* statesT = (ushort_t*)(w + 33554432);      // [32M,48M): chunk states bf16 [p][n]
    ushort_t* WoutT   = (ushort_t*)(w + 33554432);      // reuses statesT region AFTER chunk_y
    // ---- d_out (16.78 MB fp32) doubles as scratch until GEMM2 overwrites it ----
    char* dscr = (char*)d_out;
    ushort_t* xpbc  = (ushort_t*)(dscr);                // [0, 2M): pre-conv B|C
    float*    dtv   = (float*)(dscr + 2097152);         // [2M, 2.5M)
    float*    dalog = (float*)(dscr + 2621440);         // [2.5M, 3M)
    float*    cdec  = (float*)(dscr + 3145728);         // [3M, 3M+8K)
    ushort_t* WinT  = (ushort_t*)(dscr + 4194304);      // [4M, 6.25M): W_in^T bf16 (dead before gemm2)
    ushort_t* xb    = (ushort_t*)(dscr + 8388608);      // [8M, 16M): x bf16 (dead before gemm2)

    cast_f32_bf16_k<<<(MROWS * DMODEL / 8 + 255) / 256, 256, 0, stream>>>(x, xb, MROWS * DMODEL / 8);
    transpose_f32_bf16_k<<<dim3((NPROJ + 31) / 32, DMODEL / 32), dim3(32, 8), 0, stream>>>(W_in, WinT, DMODEL, NPROJ);
    gemm_k<0><<<dim3(18, MROWS / 128), 256, 0, stream>>>(
        xb, WinT, zbuf, xpx, xpbc, dtv, dalog, dt_b, A_log, nullptr,
        MROWS, NPROJ, DMODEL);
    chunk_state_k<<<dim3(NCHUNK, NHEADS, BATCH), 256, 0, stream>>>(
        xpx, xpbc, dtv, dalog, conv_w, conv_b, statesT, cdec);
    scan_combine_k<<<BATCH * NHEADS * 4, 256, 0, stream>>>(statesT, cdec);
    chunk_y_k<<<dim3(NCHUNK, NHEADS, BATCH), 256, 0, stream>>>(
        xpx, xpbc, zbuf, dtv, dalog, statesT, conv_w, conv_b, Dp);
    rmsnorm_k<<<MROWS, 256, 0, stream>>>(zbuf, nw);
    // statesT dead; transpose W_out into its region, then GEMM2
    transpose_f32_bf16_k<<<dim3(DMODEL / 32, DINNER / 32), dim3(32, 8), 0, stream>>>(W_out, WoutT, DINNER, DMODEL);
    gemm_k<1><<<dim3(4, MROWS / 128), 256, 0, stream>>>(
        zbuf, WoutT, nullptr, nullptr, nullptr, nullptr, nullptr, nullptr,
        nullptr, out, MROWS, DMODEL, DINNER);
}

// Round 9
// 316.314 us; speedup vs baseline: 1.1262x; 1.1262x over previous
//
#include <hip/hip_runtime.h>
#include <hip/hip_bf16.h>

#define BATCH   2
#define SEQ     4096
#define DMODEL  512
#define DINNER  1024
#define DSTATE  64
#define NHEADS  16
#define HEADDIM 64
#define CONVDIM 1152
#define NPROJ   2192
#define MROWS   (BATCH*SEQ)   // 8192
#define QCH     64
#define NCHUNK  (SEQ/QCH)     // 64 chunks per batch

typedef short bf16x8 __attribute__((ext_vector_type(8)));
typedef float f32x4  __attribute__((ext_vector_type(4)));
using bf16 = __hip_bfloat16;
typedef unsigned short ushort_t;
typedef unsigned int   uint_t;

__device__ __forceinline__ float sigmoidf_(float x) { return 1.f / (1.f + __expf(-x)); }
__device__ __forceinline__ float bf2f(ushort_t u) { return __uint_as_float((uint_t)u << 16); }
__device__ __forceinline__ ushort_t f2bfu(float f) {
    bf16 h = __float2bfloat16(f);
    return *(ushort_t*)&h;
}
__device__ __forceinline__ void bf8_to_f(const ushort_t* __restrict__ p, float* __restrict__ f) {
    uint4 u = *(const uint4*)p;
    f[0] = __uint_as_float((u.x & 0xFFFFu) << 16);
    f[1] = __uint_as_float(u.x & 0xFFFF0000u);
    f[2] = __uint_as_float((u.y & 0xFFFFu) << 16);
    f[3] = __uint_as_float(u.y & 0xFFFF0000u);
    f[4] = __uint_as_float((u.z & 0xFFFFu) << 16);
    f[5] = __uint_as_float(u.z & 0xFFFF0000u);
    f[6] = __uint_as_float((u.w & 0xFFFFu) << 16);
    f[7] = __uint_as_float(u.w & 0xFFFF0000u);
}
__device__ __forceinline__ uint4 f8_to_bf(const float* __restrict__ f) {
    union { ushort_t s[8]; uint4 u; } r;
#pragma unroll
    for (int i = 0; i < 8; i++) r.s[i] = f2bfu(f[i]);
    return r.u;
}

// ---------------------------------------------------------------- fp32 -> bf16 cast (8/thread)
__global__ void cast_f32_bf16_k(const float* __restrict__ in, ushort_t* __restrict__ out, int n8)
{
    int i = blockIdx.x * 256 + threadIdx.x;
    if (i >= n8) return;
    float f[8];
    *(float4*)(f + 0) = ((const float4*)in)[i * 2 + 0];
    *(float4*)(f + 4) = ((const float4*)in)[i * 2 + 1];
    ((uint4*)out)[i] = f8_to_bf(f);
}

// ---------------------------------------------------------------- transpose fp32 in[R][C] -> bf16 out[C][R]
__global__ void transpose_f32_bf16_k(const float* __restrict__ in, ushort_t* __restrict__ out,
                                     int R, int C)
{
    __shared__ __align__(16) ushort_t tile[32][33];
    int c0 = blockIdx.x * 32, r0 = blockIdx.y * 32;
    int tx = threadIdx.x, ty = threadIdx.y;
#pragma unroll
    for (int i = 0; i < 32; i += 8) {
        int r = r0 + ty + i, c = c0 + tx;
        tile[ty + i][tx] = (r < R && c < C) ? f2bfu(in[(size_t)r * C + c]) : (ushort_t)0;
    }
    __syncthreads();
#pragma unroll
    for (int i = 0; i < 32; i += 8) {
        int orow = c0 + ty + i, ocol = r0 + tx;
        if (orow < C && ocol < R) out[(size_t)orow * R + ocol] = tile[tx][ty + i];
    }
}

// ---------------------------------------------------------------- GEMM (bf16 MFMA), both operands bf16 k-contig
// C[M][N] = A[M][K] @ Bt[N][K]^T.  MODE 0: split epilogue (z/xpx/xpbc via LDS-staged
// coalesced stores; dt block scalar).  MODE 1: fp32 out (already full-line coalesced).
// K-loop software-pipelined: next iteration's global loads issued under the MFMA phase.
template<int MODE>
__global__ __launch_bounds__(256, 3)
void gemm_k(const ushort_t* __restrict__ A, const ushort_t* __restrict__ Bt,
            ushort_t* __restrict__ zbuf, ushort_t* __restrict__ xpx,
            ushort_t* __restrict__ xpbc, float* __restrict__ dtv,
            float* __restrict__ dalog, const float* __restrict__ dt_b,
            const float* __restrict__ A_log, float* __restrict__ outf,
            int M, int N, int K)
{
    constexpr int SA = 72;
    constexpr int SC = 132;                       // C-tile stride (bank-spread)
    __shared__ __align__(16) ushort_t smem[2 * 128 * SA];   // As|Bs, reused as Cs
    ushort_t* As = smem;
    ushort_t* Bs = smem + 128 * SA;
    ushort_t* Cs = smem;                          // 128*132 = 33792 <= 36864

    const int tid  = threadIdx.x;
    const int wave = tid >> 6, lane = tid & 63;
    const int quad = lane >> 4, l16 = lane & 15;
    const int wm = (wave >> 1) * 64, wn = (wave & 1) * 64;
    const int m0 = blockIdx.y * 128, n0 = blockIdx.x * 128;

    const int srow = tid >> 1, scol = (tid & 1) * 32;  // 2 threads/row, 32 bf16 each
    const int  gn     = n0 + srow;
    const bool bvalid = (gn < N);

    f32x4 acc[4][4];
#pragma unroll
    for (int i = 0; i < 4; i++)
#pragma unroll
        for (int j = 0; j < 4; j++) acc[i][j] = (f32x4){0.f, 0.f, 0.f, 0.f};

    uint4 av[4], bv[4];
    {   // prologue load k0=0
        const uint4* ap = (const uint4*)(A + (size_t)(m0 + srow) * K + scol);
#pragma unroll
        for (int j = 0; j < 4; j++) av[j] = ap[j];
        if (bvalid) {
            const uint4* bp = (const uint4*)(Bt + (size_t)gn * K + scol);
#pragma unroll
            for (int j = 0; j < 4; j++) bv[j] = bp[j];
        } else {
#pragma unroll
            for (int j = 0; j < 4; j++) bv[j] = (uint4){0u, 0u, 0u, 0u};
        }
    }

    for (int k0 = 0; k0 < K; k0 += 64) {
        __syncthreads();                           // prev MFMA reads done
        {
            uint4* asw = (uint4*)(&As[srow * SA + scol]);
            uint4* bsw = (uint4*)(&Bs[srow * SA + scol]);
#pragma unroll
            for (int j = 0; j < 4; j++) { asw[j] = av[j]; bsw[j] = bv[j]; }
        }
        __syncthreads();                           // LDS ready
        if (k0 + 64 < K) {                         // prefetch next (overlaps MFMA)
            const uint4* ap = (const uint4*)(A + (size_t)(m0 + srow) * K + k0 + 64 + scol);
#pragma unroll
            for (int j = 0; j < 4; j++) av[j] = ap[j];
            if (bvalid) {
                const uint4* bp = (const uint4*)(Bt + (size_t)gn * K + k0 + 64 + scol);
#pragma unroll
                for (int j = 0; j < 4; j++) bv[j] = bp[j];
            }
        }
#pragma unroll
        for (int kk = 0; kk < 64; kk += 32) {
            bf16x8 af[4], bfr[4];
#pragma unroll
            for (int i = 0; i < 4; i++)
                af[i] = *(const bf16x8*)(&As[(wm + i * 16 + l16) * SA + kk + quad * 8]);
#pragma unroll
            for (int j = 0; j < 4; j++)
                bfr[j] = *(const bf16x8*)(&Bs[(wn + j * 16 + l16) * SA + kk + quad * 8]);
#pragma unroll
            for (int i = 0; i < 4; i++)
#pragma unroll
                for (int j = 0; j < 4; j++)
                    acc[i][j] = __builtin_amdgcn_mfma_f32_16x16x32_bf16(af[i], bfr[j], acc[i][j], 0, 0, 0);
        }
    }
    // ---- epilogue: C/D layout col=lane&15, row=quad*4+reg (m89/m91 verified) ----
    if (MODE == 1) {
#pragma unroll
        for (int i = 0; i < 4; i++)
#pragma unroll
            for (int j = 0; j < 4; j++) {
                int col = n0 + wn + j * 16 + l16;
                int rowb = m0 + wm + i * 16 + quad * 4;
#pragma unroll
                for (int r = 0; r < 4; r++)
                    outf[(size_t)(rowb + r) * N + col] = acc[i][j][r];
            }
    } else if (n0 == 2176) {
        // dt block: scalar path with fused softplus (cols 2176..2191 valid)
#pragma unroll
        for (int i = 0; i < 4; i++)
#pragma unroll
            for (int j = 0; j < 4; j++) {
                int col = n0 + wn + j * 16 + l16;
                int rowb = m0 + wm + i * 16 + quad * 4;
                if (col < N) {
                    int hh = col - 2176;
#pragma unroll
                    for (int r = 0; r < 4; r++) {
                        float v = acc[i][j][r];
                        size_t g = (size_t)(rowb + r);
                        float raw = v + dt_b[hh];
                        float sp  = (raw > 20.f) ? raw : log1pf(__expf(raw));
                        dtv  [g * NHEADS + hh] = sp;
                        dalog[g * NHEADS + hh] = -__expf(A_log[hh]) * sp;
                    }
                }
            }
    } else {
        // LDS-staged coalesced bf16 tile store (full 64B lines, 256B runs per 16 lanes)
        __syncthreads();                           // all MFMA LDS reads done
#pragma unroll
        for (int i = 0; i < 4; i++)
#pragma unroll
            for (int j = 0; j < 4; j++)
#pragma unroll
                for (int r = 0; r < 4; r++)
                    Cs[(wm + i * 16 + quad * 4 + r) * SC + wn + j * 16 + l16] = f2bfu(acc[i][j][r]);
        __syncthreads();
        ushort_t* dst; int ld, coff;
        if (n0 < 1024)      { dst = zbuf; ld = 1024; coff = n0; }
        else if (n0 < 2048) { dst = xpx;  ld = 1024; coff = n0 - 1024; }
        else                { dst = xpbc; ld = 128;  coff = 0; }
#pragma unroll
        for (int jj = 0; jj < 8; jj++) {
            int idx = jj * 256 + tid;
            int row = idx >> 4, cq = (idx & 15) * 8;
            uint4 v = *(const uint4*)&Cs[row * SC + cq];
            *(uint4*)&dst[(size_t)(m0 + row) * ld + coff + cq] = v;
        }
    }
}

// ---------------------------------------------------------------- per-chunk state outer product (MFMA) — unchanged
// statesT[c][b][h][p][n] = sum_t xs[t][p] * (wc_t * B[t][n])    (bf16 out, TRANSPOSED [p][n])
__global__ __launch_bounds__(256, 2)
void chunk_state_k(const ushort_t* __restrict__ xpx, const ushort_t* __restrict__ xpbc,
                   const float* __restrict__ dtv, const float* __restrict__ dalog,
                   const float* __restrict__ cw, const float* __restrict__ cb,
                   ushort_t* __restrict__ statesT, float* __restrict__ cdecay)
{
    const int c = blockIdx.x, h = blockIdx.y, b = blockIdx.z;
    __shared__ __align__(16) ushort_t xsT[64 * 72];   // [p][t]  t-contig
    __shared__ __align__(16) ushort_t BwT[64 * 72];   // [n][t]  t-contig, weighted by wc[t]
    __shared__ float wc[64];
    const int tid = threadIdx.x;
    const int ts = tid >> 2, q4 = (tid & 3) * 16;
    const int l = c * QCH + ts;
    if (tid < 64) {
        size_t gl = ((size_t)b * SEQ + c * QCH + tid) * NHEADS + h;
        float v = dalog[gl];
#pragma unroll
        for (int off = 1; off < 64; off <<= 1) {
            float u = __shfl_up(v, off, 64);
            if (tid >= off) v += u;
        }
        float tot = __shfl(v, 63, 64);
        wc[tid] = __expf(tot - v) * dtv[gl];
        if (tid == 63) cdecay[(c * BATCH + b) * NHEADS + h] = __expf(tot);
    }
    __syncthreads();
    {
        const int ch0 = h * HEADDIM + q4;
        float a16[16];
#pragma unroll
        for (int i = 0; i < 16; i++) a16[i] = cb[ch0 + i];
#pragma unroll
        for (int j = 0; j < 4; j++) {
            int ll = l - 3 + j;
            if (ll >= 0) {
                float xv[16];
                const ushort_t* rp = xpx + ((size_t)b * SEQ + ll) * 1024 + ch0;
                bf8_to_f(rp, xv); bf8_to_f(rp + 8, xv + 8);
#pragma unroll
                for (int i = 0; i < 16; i++) a16[i] += cw[(ch0 + i) * 4 + j] * xv[i];
            }
        }
#pragma unroll
        for (int i = 0; i < 16; i++) { float v = a16[i]; xsT[(q4 + i) * 72 + ts] = f2bfu(v * sigmoidf_(v)); }
    }
    {
        float b16[16];
#pragma unroll
        for (int i = 0; i < 16; i++) b16[i] = cb[1024 + q4 + i];
#pragma unroll
        for (int j = 0; j < 4; j++) {
            int ll = l - 3 + j;
            if (ll >= 0) {
                float bv[16];
                const ushort_t* rp = xpbc + ((size_t)b * SEQ + ll) * 128;
                bf8_to_f(rp + q4, bv); bf8_to_f(rp + q4 + 8, bv + 8);
#pragma unroll
                for (int i = 0; i < 16; i++) b16[i] += cw[(1024 + q4 + i) * 4 + j] * bv[i];
            }
        }
        const float wt = wc[ts];
#pragma unroll
        for (int i = 0; i < 16; i++) { float v = b16[i]; BwT[(q4 + i) * 72 + ts] = f2bfu(v * sigmoidf_(v) * wt); }
    }
    __syncthreads();
    const int wave = tid >> 6, lane = tid & 63;
    const int quad = lane >> 4, l16 = lane & 15;
    f32x4 acc[4];
#pragma unroll
    for (int j = 0; j < 4; j++) acc[j] = (f32x4){0.f, 0.f, 0.f, 0.f};
#pragma unroll
    for (int kk = 0; kk < 64; kk += 32) {
        bf16x8 af = *(const bf16x8*)(&xsT[(wave * 16 + l16) * 72 + kk + quad * 8]);
#pragma unroll
        for (int j = 0; j < 4; j++) {
            bf16x8 bf_ = *(const bf16x8*)(&BwT[(j * 16 + l16) * 72 + kk + quad * 8]);
            acc[j] = __builtin_amdgcn_mfma_f32_16x16x32_bf16(af, bf_, acc[j], 0, 0, 0);
        }
    }
    ushort_t* base = statesT + ((size_t)(c * BATCH + b) * NHEADS + h) * (HEADDIM * DSTATE);
#pragma unroll
    for (int j = 0; j < 4; j++)
#pragma unroll
        for (int r = 0; r < 4; r++)
            base[(wave * 16 + quad * 4 + r) * 64 + j * 16 + l16] = f2bfu(acc[j][r]);
}

// ---------------------------------------------------------------- sequential chunk combine — unchanged
__global__ void scan_combine_k(ushort_t* __restrict__ states, const float* __restrict__ cdecay)
{
    const int blk = blockIdx.x;           // 128 = 2*16*4
    const int quarter = blk & 3;
    const int h = (blk >> 2) & 15;
    const int b = blk >> 6;
    const int tid = threadIdx.x;
    __shared__ float dec[64];
    if (tid < 64) dec[tid] = cdecay[(tid * BATCH + b) * NHEADS + h];
    __syncthreads();
    const size_t cstride = (size_t)BATCH * NHEADS * HEADDIM * DSTATE;  // elements
    ushort_t* base = states + ((size_t)b * NHEADS + h) * (HEADDIM * DSTATE) + quarter * 1024 + tid * 4;
    float sx = 0.f, sy = 0.f, sz = 0.f, sw = 0.f;
    uint2 pre[4];
#pragma unroll
    for (int j = 0; j < 4; j++) pre[j] = *(const uint2*)(base + j * cstride);
    for (int c = 0; c < NCHUNK; c++) {
        uint2 Sc = pre[c & 3];
        if (c + 4 < NCHUNK) pre[c & 3] = *(const uint2*)(base + (size_t)(c + 4) * cstride);
        float d = dec[c];
        uint2 o;
        o.x = (uint_t)f2bfu(sx) | ((uint_t)f2bfu(sy) << 16);
        o.y = (uint_t)f2bfu(sz) | ((uint_t)f2bfu(sw) << 16);
        *(uint2*)(base + (size_t)c * cstride) = o;
        sx = d * sx + __uint_as_float((Sc.x & 0xFFFFu) << 16);
        sy = d * sy + __uint_as_float(Sc.x & 0xFFFF0000u);
        sz = d * sz + __uint_as_float((Sc.y & 0xFFFFu) << 16);
        sw = d * sw + __uint_as_float(Sc.y & 0xFFFF0000u);
    }
}

// ---------------------------------------------------------------- per-chunk y (MFMA) — unchanged
__global__ __launch_bounds__(256, 2)
void chunk_y_k(const ushort_t* __restrict__ xpx, const ushort_t* __restrict__ xpbc,
               ushort_t* zio,
               const float* __restrict__ dtv, const float* __restrict__ dalog,
               const ushort_t* __restrict__ statesT, const float* __restrict__ cw,
               const float* __restrict__ cb, const float* __restrict__ Dp)
{
    const int c = blockIdx.x, h = blockIdx.y, b = blockIdx.z;
    __shared__ __align__(16) ushort_t CLb [64 * 72];  // C[t][n] n-contig
    __shared__ __align__(16) ushort_t BLb [64 * 72];  // B[s][n] n-contig -> ybuf[t][p]
    __shared__ __align__(16) ushort_t xsT [64 * 72];  // xs^T [p][t] t-contig
    __shared__ __align__(16) ushort_t attL[64 * 72];  // att[t][s] s-contig
    __shared__ float cum[64], wdt[64];
    const int tid = threadIdx.x;
    const int ts = tid >> 2, q4 = (tid & 3) * 16;
    const int l = c * QCH + ts;
    const float Dh = Dp[h];
    {
        const int ch0 = h * HEADDIM + q4;
        float a16[16];
#pragma unroll
        for (int i = 0; i < 16; i++) a16[i] = cb[ch0 + i];
#pragma unroll
        for (int j = 0; j < 4; j++) {
            int ll = l - 3 + j;
            if (ll >= 0) {
                float xv[16];
                const ushort_t* rp = xpx + ((size_t)b * SEQ + ll) * 1024 + ch0;
                bf8_to_f(rp, xv); bf8_to_f(rp + 8, xv + 8);
#pragma unroll
                for (int i = 0; i < 16; i++) a16[i] += cw[(ch0 + i) * 4 + j] * xv[i];
            }
        }
#pragma unroll
        for (int i = 0; i < 16; i++) { float v = a16[i]; xsT[(q4 + i) * 72 + ts] = f2bfu(v * sigmoidf_(v)); }
    }
    {
        float b16[16], c16[16];
#pragma unroll
        for (int i = 0; i < 16; i++) { b16[i] = cb[1024 + q4 + i]; c16[i] = cb[1088 + q4 + i]; }
#pragma unroll
        for (int j = 0; j < 4; j++) {
            int ll = l - 3 + j;
            if (ll >= 0) {
                const ushort_t* rp = xpbc + ((size_t)b * SEQ + ll) * 128;
                float bv[16], cv[16];
                bf8_to_f(rp + q4, bv);      bf8_to_f(rp + q4 + 8, bv + 8);
                bf8_to_f(rp + 64 + q4, cv); bf8_to_f(rp + 64 + q4 + 8, cv + 8);
#pragma unroll
                for (int i = 0; i < 16; i++) {
                    b16[i] += cw[(1024 + q4 + i) * 4 + j] * bv[i];
                    c16[i] += cw[(1088 + q4 + i) * 4 + j] * cv[i];
                }
            }
        }
        float bs[16], cs[16];
#pragma unroll
        for (int i = 0; i < 16; i++) {
            float v = b16[i]; bs[i] = v * sigmoidf_(v);
            float u = c16[i]; cs[i] = u * sigmoidf_(u);
        }
        *(uint4*)&BLb[ts * 72 + q4]     = f8_to_bf(bs);
        *(uint4*)&BLb[ts * 72 + q4 + 8] = f8_to_bf(bs + 8);
        *(uint4*)&CLb[ts * 72 + q4]     = f8_to_bf(cs);
        *(uint4*)&CLb[ts * 72 + q4 + 8] = f8_to_bf(cs + 8);
    }
    if (tid < 64) {
        size_t gl = ((size_t)b * SEQ + c * QCH + tid) * NHEADS + h;
        float v = dalog[gl];
#pragma unroll
        for (int off = 1; off < 64; off <<= 1) {
            float u = __shfl_up(v, off, 64);
            if (tid >= off) v += u;
        }
        cum[tid] = v;
        wdt[tid] = dtv[gl];
    }
    __syncthreads();
    const int wave = tid >> 6, lane = tid & 63;
    const int quad = lane >> 4, l16 = lane & 15;
    {
        f32x4 sacc[4];
#pragma unroll
        for (int j = 0; j < 4; j++) sacc[j] = (f32x4){0.f, 0.f, 0.f, 0.f};
#pragma unroll
        for (int kk = 0; kk < 64; kk += 32) {
            bf16x8 af = *(const bf16x8*)(&CLb[(wave * 16 + l16) * 72 + kk + quad * 8]);
#pragma unroll
            for (int j = 0; j < 4; j++) {
                bf16x8 bf_ = *(const bf16x8*)(&BLb[(j * 16 + l16) * 72 + kk + quad * 8]);
                sacc[j] = __builtin_amdgcn_mfma_f32_16x16x32_bf16(af, bf_, sacc[j], 0, 0, 0);
            }
        }
#pragma unroll
        for (int r = 0; r < 4; r++) {
            const int t = wave * 16 + quad * 4 + r;
            const float ct = cum[t];
#pragma unroll
            for (int j = 0; j < 4; j++) {
                const int s = j * 16 + l16;
                float a = (s <= t) ? sacc[j][r] * __expf(ct - cum[s]) * wdt[s] : 0.f;
                attL[t * 72 + s] = f2bfu(a);
            }
        }
    }
    __syncthreads();
    {
        f32x4 accY[4], accI[4];
#pragma unroll
        for (int j = 0; j < 4; j++) { accY[j] = (f32x4){0.f, 0.f, 0.f, 0.f}; accI[j] = (f32x4){0.f, 0.f, 0.f, 0.f}; }
        const ushort_t* spg = statesT + ((size_t)(c * BATCH + b) * NHEADS + h) * (HEADDIM * DSTATE);
#pragma unroll
        for (int kk = 0; kk < 64; kk += 32) {
            bf16x8 a2 = *(const bf16x8*)(&attL[(wave * 16 + l16) * 72 + kk + quad * 8]);
            bf16x8 a3 = *(const bf16x8*)(&CLb [(wave * 16 + l16) * 72 + kk + quad * 8]);
#pragma unroll
            for (int j = 0; j < 4; j++) {
                bf16x8 b2 = *(const bf16x8*)(&xsT[(j * 16 + l16) * 72 + kk + quad * 8]);
                accY[j] = __builtin_amdgcn_mfma_f32_16x16x32_bf16(a2, b2, accY[j], 0, 0, 0);
                bf16x8 b3 = *(const bf16x8*)(spg + (j * 16 + l16) * 64 + kk + quad * 8);
                accI[j] = __builtin_amdgcn_mfma_f32_16x16x32_bf16(a3, b3, accI[j], 0, 0, 0);
            }
        }
#pragma unroll
        for (int r = 0; r < 4; r++) {
            const int t = wave * 16 + quad * 4 + r;
            const float et = __expf(cum[t]);
#pragma unroll
            for (int j = 0; j < 4; j++) {
                const int p = j * 16 + l16;
                float xv = bf2f(xsT[p * 72 + t]);
                float y = accY[j][r] + et * accI[j][r] + Dh * xv;
                BLb[t * 72 + p] = f2bfu(y);
            }
        }
    }
    __syncthreads();
    {
        ushort_t* zrow = zio + ((size_t)b * SEQ + l) * DINNER + h * HEADDIM + q4;
        float zv[16], yv[16], o[16];
        bf8_to_f(zrow, zv); bf8_to_f(zrow + 8, zv + 8);
        bf8_to_f(&BLb[ts * 72 + q4], yv); bf8_to_f(&BLb[ts * 72 + q4 + 8], yv + 8);
#pragma unroll
        for (int j = 0; j < 16; j++) {
            float z = zv[j];
            o[j] = yv[j] * z * sigmoidf_(z);
        }
        *(uint4*)(zrow)     = f8_to_bf(o);
        *(uint4*)(zrow + 8) = f8_to_bf(o + 8);
    }
}

// ---------------------------------------------------------------- RMSNorm (in place, bf16) — unchanged
__global__ void rmsnorm_k(ushort_t* yio, const float* __restrict__ nw)
{
    const int row = blockIdx.x, tid = threadIdx.x;
    uint2 u = *(const uint2*)(yio + (size_t)row * DINNER + tid * 4);
    float v0 = __uint_as_float((u.x & 0xFFFFu) << 16);
    float v1 = __uint_as_float(u.x & 0xFFFF0000u);
    float v2 = __uint_as_float((u.y & 0xFFFFu) << 16);
    float v3 = __uint_as_float(u.y & 0xFFFF0000u);
    float ss = v0 * v0 + v1 * v1 + v2 * v2 + v3 * v3;
#pragma unroll
    for (int off = 32; off >= 1; off >>= 1) ss += __shfl_xor(ss, off, 64);
    __shared__ float part[4];
    const int wave = tid >> 6;
    if ((tid & 63) == 0) part[wave] = ss;
    __syncthreads();
    float tot = part[0] + part[1] + part[2] + part[3];
    float scale = rsqrtf(tot * (1.f / DINNER) + 1e-5f);
    uint2 o;
    o.x = (uint_t)f2bfu(v0 * scale * nw[tid * 4 + 0]) | ((uint_t)f2bfu(v1 * scale * nw[tid * 4 + 1]) << 16);
    o.y = (uint_t)f2bfu(v2 * scale * nw[tid * 4 + 2]) | ((uint_t)f2bfu(v3 * scale * nw[tid * 4 + 3]) << 16);
    *(uint2*)(yio + (size_t)row * DINNER + tid * 4) = o;
}

// ---------------------------------------------------------------- launch
extern "C" void kernel_launch(void* const* d_in, const int* in_sizes, int n_in,
                              void* d_out, int out_size, void* d_ws, size_t ws_size,
                              hipStream_t stream)
{
    const float* x      = (const float*)d_in[0];
    const float* W_in   = (const float*)d_in[1];
    const float* conv_w = (const float*)d_in[2];
    const float* conv_b = (const float*)d_in[3];
    const float* dt_b   = (const float*)d_in[4];
    const float* A_log  = (const float*)d_in[5];
    const float* Dp     = (const float*)d_in[6];
    const float* nw     = (const float*)d_in[7];
    const float* W_out  = (const float*)d_in[8];
    float* out = (float*)d_out;                    // (2,4096,512) fp32

    // ---- workspace (48 MiB high-water, unchanged) ----
    char* w = (char*)d_ws;
    ushort_t* zbuf    = (ushort_t*)(w);                 // [0,16M): z -> y -> yn (in place)
    ushort_t* xpx     = (ushort_t*)(w + 16777216);      // [16M,32M): pre-conv xBC x-part
    ushort_t* statesT = (ushort_t*)(w + 33554432);      // [32M,48M): chunk states bf16 [p][n]
    ushort_t* WoutT   = (ushort_t*)(w + 33554432);      // reuses statesT region AFTER chunk_y
    // ---- d_out (16.78 MB fp32) doubles as scratch until GEMM2 overwrites it ----
    char* dscr = (char*)d_out;
    ushort_t* xpbc  = (ushort_t*)(dscr);                // [0, 2M): pre-conv B|C
    float*    dtv   = (float*)(dscr + 2097152);         // [2M, 2.5M)
    float*    dalog = (float*)(dscr + 2621440);         // [2.5M, 3M)
    float*    cdec  = (float*)(dscr + 3145728);         // [3M, 3M+8K)
    ushort_t* WinT  = (ushort_t*)(dscr + 4194304);      // [4M, 6.25M): W_in^T bf16 (dead before gemm2)
    ushort_t* xb    = (ushort_t*)(dscr + 8388608);      // [8M, 16M): x bf16 (dead before gemm2)

    cast_f32_bf16_k<<<(MROWS * DMODEL / 8 + 255) / 256, 256, 0, stream>>>(x, xb, MROWS * DMODEL / 8);
    transpose_f32_bf16_k<<<dim3((NPROJ + 31) / 32, DMODEL / 32), dim3(32, 8), 0, stream>>>(W_in, WinT, DMODEL, NPROJ);
    gemm_k<0><<<dim3(18, MROWS / 128), 256, 0, stream>>>(
        xb, WinT, zbuf, xpx, xpbc, dtv, dalog, dt_b, A_log, nullptr,
        MROWS, NPROJ, DMODEL);
    chunk_state_k<<<dim3(NCHUNK, NHEADS, BATCH), 256, 0, stream>>>(
        xpx, xpbc, dtv, dalog, conv_w, conv_b, statesT, cdec);
    scan_combine_k<<<BATCH * NHEADS * 4, 256, 0, stream>>>(statesT, cdec);
    chunk_y_k<<<dim3(NCHUNK, NHEADS, BATCH), 256, 0, stream>>>(
        xpx, xpbc, zbuf, dtv, dalog, statesT, conv_w, conv_b, Dp);
    rmsnorm_k<<<MROWS, 256, 0, stream>>>(zbuf, nw);
    // statesT dead; transpose W_out into its region, then GEMM2
    transpose_f32_bf16_k<<<dim3(DMODEL / 32, DINNER / 32), dim3(32, 8), 0, stream>>>(W_out, WoutT, DINNER, DMODEL);
    gemm_k<1><<<dim3(4, MROWS / 128), 256, 0, stream>>>(
        zbuf, WoutT, nullptr, nullptr, nullptr, nullptr, nullptr, nullptr,
        nullptr, out, MROWS, DMODEL, DINNER);
}

// Round 10
// 275.635 us; speedup vs baseline: 1.2924x; 1.1476x over previous
//
#include <hip/hip_runtime.h>
#include <hip/hip_bf16.h>

#define BATCH   2
#define SEQ     4096
#define DMODEL  512
#define DINNER  1024
#define DSTATE  64
#define NHEADS  16
#define HEADDIM 64
#define CONVDIM 1152
#define NPROJ   2192
#define MROWS   (BATCH*SEQ)   // 8192
#define QCH     64
#define NCHUNK  (SEQ/QCH)     // 64 chunks per batch

typedef short bf16x8 __attribute__((ext_vector_type(8)));
typedef float f32x4  __attribute__((ext_vector_type(4)));
using bf16 = __hip_bfloat16;
typedef unsigned short ushort_t;
typedef unsigned int   uint_t;

__device__ __forceinline__ float sigmoidf_(float x) { return 1.f / (1.f + __expf(-x)); }
__device__ __forceinline__ float bf2f(ushort_t u) { return __uint_as_float((uint_t)u << 16); }
__device__ __forceinline__ ushort_t f2bfu(float f) {
    bf16 h = __float2bfloat16(f);
    return *(ushort_t*)&h;
}
__device__ __forceinline__ void bf8_to_f(const ushort_t* __restrict__ p, float* __restrict__ f) {
    uint4 u = *(const uint4*)p;
    f[0] = __uint_as_float((u.x & 0xFFFFu) << 16);
    f[1] = __uint_as_float(u.x & 0xFFFF0000u);
    f[2] = __uint_as_float((u.y & 0xFFFFu) << 16);
    f[3] = __uint_as_float(u.y & 0xFFFF0000u);
    f[4] = __uint_as_float((u.z & 0xFFFFu) << 16);
    f[5] = __uint_as_float(u.z & 0xFFFF0000u);
    f[6] = __uint_as_float((u.w & 0xFFFFu) << 16);
    f[7] = __uint_as_float(u.w & 0xFFFF0000u);
}
__device__ __forceinline__ uint4 f8_to_bf(const float* __restrict__ f) {
    union { ushort_t s[8]; uint4 u; } r;
#pragma unroll
    for (int i = 0; i < 8; i++) r.s[i] = f2bfu(f[i]);
    return r.u;
}

// ---------------------------------------------------------------- fp32 -> bf16 cast (8/thread)
__global__ void cast_f32_bf16_k(const float* __restrict__ in, ushort_t* __restrict__ out, int n8)
{
    int i = blockIdx.x * 256 + threadIdx.x;
    if (i >= n8) return;
    float f[8];
    *(float4*)(f + 0) = ((const float4*)in)[i * 2 + 0];
    *(float4*)(f + 4) = ((const float4*)in)[i * 2 + 1];
    ((uint4*)out)[i] = f8_to_bf(f);
}

// ---------------------------------------------------------------- transpose fp32 in[R][C] -> bf16 out[C][R]
__global__ void transpose_f32_bf16_k(const float* __restrict__ in, ushort_t* __restrict__ out,
                                     int R, int C)
{
    __shared__ __align__(16) ushort_t tile[32][33];
    int c0 = blockIdx.x * 32, r0 = blockIdx.y * 32;
    int tx = threadIdx.x, ty = threadIdx.y;
#pragma unroll
    for (int i = 0; i < 32; i += 8) {
        int r = r0 + ty + i, c = c0 + tx;
        tile[ty + i][tx] = (r < R && c < C) ? f2bfu(in[(size_t)r * C + c]) : (ushort_t)0;
    }
    __syncthreads();
#pragma unroll
    for (int i = 0; i < 32; i += 8) {
        int orow = c0 + ty + i, ocol = r0 + tx;
        if (orow < C && ocol < R) out[(size_t)orow * R + ocol] = tile[tx][ty + i];
    }
}

// ---------------------------------------------------------------- B/C conv+SiLU prekernel (dedups 16x per-head work)
// bcc[row][0..127] = silu(conv(xpbc)) ; 8 channels/thread
__global__ void bcconv_k(const ushort_t* __restrict__ xpbc, const float* __restrict__ cw,
                         const float* __restrict__ cb, ushort_t* __restrict__ bcc)
{
    int idx = blockIdx.x * 256 + threadIdx.x;     // MROWS*16
    int row = idx >> 4, c8 = (idx & 15) * 8;
    int l = row & (SEQ - 1);
    float acc[8];
#pragma unroll
    for (int i = 0; i < 8; i++) acc[i] = cb[1024 + c8 + i];
#pragma unroll
    for (int j = 0; j < 4; j++) {
        int ll = l - 3 + j;
        if (ll >= 0) {
            float v[8];
            bf8_to_f(xpbc + (size_t)(row - 3 + j) * 128 + c8, v);
#pragma unroll
            for (int i = 0; i < 8; i++) acc[i] += cw[(1024 + c8 + i) * 4 + j] * v[i];
        }
    }
#pragma unroll
    for (int i = 0; i < 8; i++) { float v = acc[i]; acc[i] = v * sigmoidf_(v); }
    *(uint4*)(bcc + (size_t)row * 128 + c8) = f8_to_bf(acc);
}

// ---------------------------------------------------------------- GEMM (bf16 MFMA) — unchanged from R9 (proven)
template<int MODE>
__global__ __launch_bounds__(256, 3)
void gemm_k(const ushort_t* __restrict__ A, const ushort_t* __restrict__ Bt,
            ushort_t* __restrict__ zbuf, ushort_t* __restrict__ xpx,
            ushort_t* __restrict__ xpbc, float* __restrict__ dtv,
            float* __restrict__ dalog, const float* __restrict__ dt_b,
            const float* __restrict__ A_log, float* __restrict__ outf,
            int M, int N, int K)
{
    constexpr int SA = 72;
    constexpr int SC = 132;
    __shared__ __align__(16) ushort_t smem[2 * 128 * SA];
    ushort_t* As = smem;
    ushort_t* Bs = smem + 128 * SA;
    ushort_t* Cs = smem;

    const int tid  = threadIdx.x;
    const int wave = tid >> 6, lane = tid & 63;
    const int quad = lane >> 4, l16 = lane & 15;
    const int wm = (wave >> 1) * 64, wn = (wave & 1) * 64;
    const int m0 = blockIdx.y * 128, n0 = blockIdx.x * 128;

    const int srow = tid >> 1, scol = (tid & 1) * 32;
    const int  gn     = n0 + srow;
    const bool bvalid = (gn < N);

    f32x4 acc[4][4];
#pragma unroll
    for (int i = 0; i < 4; i++)
#pragma unroll
        for (int j = 0; j < 4; j++) acc[i][j] = (f32x4){0.f, 0.f, 0.f, 0.f};

    uint4 av[4], bv[4];
    {
        const uint4* ap = (const uint4*)(A + (size_t)(m0 + srow) * K + scol);
#pragma unroll
        for (int j = 0; j < 4; j++) av[j] = ap[j];
        if (bvalid) {
            const uint4* bp = (const uint4*)(Bt + (size_t)gn * K + scol);
#pragma unroll
            for (int j = 0; j < 4; j++) bv[j] = bp[j];
        } else {
#pragma unroll
            for (int j = 0; j < 4; j++) bv[j] = (uint4){0u, 0u, 0u, 0u};
        }
    }

    for (int k0 = 0; k0 < K; k0 += 64) {
        __syncthreads();
        {
            uint4* asw = (uint4*)(&As[srow * SA + scol]);
            uint4* bsw = (uint4*)(&Bs[srow * SA + scol]);
#pragma unroll
            for (int j = 0; j < 4; j++) { asw[j] = av[j]; bsw[j] = bv[j]; }
        }
        __syncthreads();
        if (k0 + 64 < K) {
            const uint4* ap = (const uint4*)(A + (size_t)(m0 + srow) * K + k0 + 64 + scol);
#pragma unroll
            for (int j = 0; j < 4; j++) av[j] = ap[j];
            if (bvalid) {
                const uint4* bp = (const uint4*)(Bt + (size_t)gn * K + k0 + 64 + scol);
#pragma unroll
                for (int j = 0; j < 4; j++) bv[j] = bp[j];
            }
        }
#pragma unroll
        for (int kk = 0; kk < 64; kk += 32) {
            bf16x8 af[4], bfr[4];
#pragma unroll
            for (int i = 0; i < 4; i++)
                af[i] = *(const bf16x8*)(&As[(wm + i * 16 + l16) * SA + kk + quad * 8]);
#pragma unroll
            for (int j = 0; j < 4; j++)
                bfr[j] = *(const bf16x8*)(&Bs[(wn + j * 16 + l16) * SA + kk + quad * 8]);
#pragma unroll
            for (int i = 0; i < 4; i++)
#pragma unroll
                for (int j = 0; j < 4; j++)
                    acc[i][j] = __builtin_amdgcn_mfma_f32_16x16x32_bf16(af[i], bfr[j], acc[i][j], 0, 0, 0);
        }
    }
    if (MODE == 1) {
#pragma unroll
        for (int i = 0; i < 4; i++)
#pragma unroll
            for (int j = 0; j < 4; j++) {
                int col = n0 + wn + j * 16 + l16;
                int rowb = m0 + wm + i * 16 + quad * 4;
#pragma unroll
                for (int r = 0; r < 4; r++)
                    outf[(size_t)(rowb + r) * N + col] = acc[i][j][r];
            }
    } else if (n0 == 2176) {
#pragma unroll
        for (int i = 0; i < 4; i++)
#pragma unroll
            for (int j = 0; j < 4; j++) {
                int col = n0 + wn + j * 16 + l16;
                int rowb = m0 + wm + i * 16 + quad * 4;
                if (col < N) {
                    int hh = col - 2176;
#pragma unroll
                    for (int r = 0; r < 4; r++) {
                        float v = acc[i][j][r];
                        size_t g = (size_t)(rowb + r);
                        float raw = v + dt_b[hh];
                        float sp  = (raw > 20.f) ? raw : log1pf(__expf(raw));
                        dtv  [g * NHEADS + hh] = sp;
                        dalog[g * NHEADS + hh] = -__expf(A_log[hh]) * sp;
                    }
                }
            }
    } else {
        __syncthreads();
#pragma unroll
        for (int i = 0; i < 4; i++)
#pragma unroll
            for (int j = 0; j < 4; j++)
#pragma unroll
                for (int r = 0; r < 4; r++)
                    Cs[(wm + i * 16 + quad * 4 + r) * SC + wn + j * 16 + l16] = f2bfu(acc[i][j][r]);
        __syncthreads();
        ushort_t* dst; int ld, coff;
        if (n0 < 1024)      { dst = zbuf; ld = 1024; coff = n0; }
        else if (n0 < 2048) { dst = xpx;  ld = 1024; coff = n0 - 1024; }
        else                { dst = xpbc; ld = 128;  coff = 0; }
#pragma unroll
        for (int jj = 0; jj < 8; jj++) {
            int idx = jj * 256 + tid;
            int row = idx >> 4, cq = (idx & 15) * 8;
            uint4 v = *(const uint4*)&Cs[row * SC + cq];
            *(uint4*)&dst[(size_t)(m0 + row) * ld + coff + cq] = v;
        }
    }
}

// ---------------------------------------------------------------- per-chunk state outer product (MFMA)
// statesT[c][b][h][p][n] = sum_t xs[t][p] * (wc_t * B[t][n])    (bf16 out, TRANSPOSED [p][n])
__global__ __launch_bounds__(256, 2)
void chunk_state_k(const ushort_t* __restrict__ xpx, const ushort_t* __restrict__ bcc,
                   const float* __restrict__ dtv, const float* __restrict__ dalog,
                   const float* __restrict__ cw, const float* __restrict__ cb,
                   ushort_t* __restrict__ statesT, float* __restrict__ cdecay)
{
    const int c = blockIdx.x, h = blockIdx.y, b = blockIdx.z;
    __shared__ __align__(16) ushort_t xsT[64 * 72];   // [p][t]  t-contig
    __shared__ __align__(16) ushort_t BwT[64 * 72];   // [n][t]  t-contig, weighted by wc[t]
    __shared__ float wc[64];
    const int tid = threadIdx.x;
    const int ts = tid >> 2, q4 = (tid & 3) * 16;
    const int l = c * QCH + ts;
    if (tid < 64) {
        size_t gl = ((size_t)b * SEQ + c * QCH + tid) * NHEADS + h;
        float v = dalog[gl];
#pragma unroll
        for (int off = 1; off < 64; off <<= 1) {
            float u = __shfl_up(v, off, 64);
            if (tid >= off) v += u;
        }
        float tot = __shfl(v, 63, 64);
        wc[tid] = __expf(tot - v) * dtv[gl];
        if (tid == 63) cdecay[(c * BATCH + b) * NHEADS + h] = __expf(tot);
    }
    __syncthreads();
    { // x: conv+silu, transposed store
        const int ch0 = h * HEADDIM + q4;
        float a16[16];
#pragma unroll
        for (int i = 0; i < 16; i++) a16[i] = cb[ch0 + i];
#pragma unroll
        for (int j = 0; j < 4; j++) {
            int ll = l - 3 + j;
            if (ll >= 0) {
                float xv[16];
                const ushort_t* rp = xpx + ((size_t)b * SEQ + ll) * 1024 + ch0;
                bf8_to_f(rp, xv); bf8_to_f(rp + 8, xv + 8);
#pragma unroll
                for (int i = 0; i < 16; i++) a16[i] += cw[(ch0 + i) * 4 + j] * xv[i];
            }
        }
#pragma unroll
        for (int i = 0; i < 16; i++) { float v = a16[i]; xsT[(q4 + i) * 72 + ts] = f2bfu(v * sigmoidf_(v)); }
    }
    { // B: load precomputed, weight, transposed store
        float bv[16];
        const ushort_t* rp = bcc + ((size_t)b * SEQ + l) * 128;
        bf8_to_f(rp + q4, bv); bf8_to_f(rp + q4 + 8, bv + 8);
        const float wt = wc[ts];
#pragma unroll
        for (int i = 0; i < 16; i++) BwT[(q4 + i) * 72 + ts] = f2bfu(bv[i] * wt);
    }
    __syncthreads();
    const int wave = tid >> 6, lane = tid & 63;
    const int quad = lane >> 4, l16 = lane & 15;
    f32x4 acc[4];
#pragma unroll
    for (int j = 0; j < 4; j++) acc[j] = (f32x4){0.f, 0.f, 0.f, 0.f};
#pragma unroll
    for (int kk = 0; kk < 64; kk += 32) {
        bf16x8 af = *(const bf16x8*)(&xsT[(wave * 16 + l16) * 72 + kk + quad * 8]);
#pragma unroll
        for (int j = 0; j < 4; j++) {
            bf16x8 bf_ = *(const bf16x8*)(&BwT[(j * 16 + l16) * 72 + kk + quad * 8]);
            acc[j] = __builtin_amdgcn_mfma_f32_16x16x32_bf16(af, bf_, acc[j], 0, 0, 0);
        }
    }
    ushort_t* base = statesT + ((size_t)(c * BATCH + b) * NHEADS + h) * (HEADDIM * DSTATE);
#pragma unroll
    for (int j = 0; j < 4; j++)
#pragma unroll
        for (int r = 0; r < 4; r++)
            base[(wave * 16 + quad * 4 + r) * 64 + j * 16 + l16] = f2bfu(acc[j][r]);
}

// ---------------------------------------------------------------- sequential chunk combine — unchanged
__global__ void scan_combine_k(ushort_t* __restrict__ states, const float* __restrict__ cdecay)
{
    const int blk = blockIdx.x;           // 128 = 2*16*4
    const int quarter = blk & 3;
    const int h = (blk >> 2) & 15;
    const int b = blk >> 6;
    const int tid = threadIdx.x;
    __shared__ float dec[64];
    if (tid < 64) dec[tid] = cdecay[(tid * BATCH + b) * NHEADS + h];
    __syncthreads();
    const size_t cstride = (size_t)BATCH * NHEADS * HEADDIM * DSTATE;  // elements
    ushort_t* base = states + ((size_t)b * NHEADS + h) * (HEADDIM * DSTATE) + quarter * 1024 + tid * 4;
    float sx = 0.f, sy = 0.f, sz = 0.f, sw = 0.f;
    uint2 pre[4];
#pragma unroll
    for (int j = 0; j < 4; j++) pre[j] = *(const uint2*)(base + j * cstride);
    for (int c = 0; c < NCHUNK; c++) {
        uint2 Sc = pre[c & 3];
        if (c + 4 < NCHUNK) pre[c & 3] = *(const uint2*)(base + (size_t)(c + 4) * cstride);
        float d = dec[c];
        uint2 o;
        o.x = (uint_t)f2bfu(sx) | ((uint_t)f2bfu(sy) << 16);
        o.y = (uint_t)f2bfu(sz) | ((uint_t)f2bfu(sw) << 16);
        *(uint2*)(base + (size_t)c * cstride) = o;
        sx = d * sx + __uint_as_float((Sc.x & 0xFFFFu) << 16);
        sy = d * sy + __uint_as_float(Sc.x & 0xFFFF0000u);
        sz = d * sz + __uint_as_float((Sc.y & 0xFFFFu) << 16);
        sw = d * sw + __uint_as_float(Sc.y & 0xFFFF0000u);
    }
}

// ---------------------------------------------------------------- per-chunk y (MFMA): att + intra + inter + D + gate
__global__ __launch_bounds__(256, 2)
void chunk_y_k(const ushort_t* __restrict__ xpx, const ushort_t* __restrict__ bcc,
               ushort_t* zio,
               const float* __restrict__ dtv, const float* __restrict__ dalog,
               const ushort_t* __restrict__ statesT, const float* __restrict__ cw,
               const float* __restrict__ cb, const float* __restrict__ Dp)
{
    const int c = blockIdx.x, h = blockIdx.y, b = blockIdx.z;
    __shared__ __align__(16) ushort_t CLb [64 * 72];  // C[t][n] n-contig
    __shared__ __align__(16) ushort_t BLb [64 * 72];  // B[s][n] n-contig -> ybuf[t][p]
    __shared__ __align__(16) ushort_t xsT [64 * 72];  // xs^T [p][t] t-contig
    __shared__ __align__(16) ushort_t attL[64 * 72];  // att[t][s] s-contig
    __shared__ float cum[64], wdt[64];
    const int tid = threadIdx.x;
    const int ts = tid >> 2, q4 = (tid & 3) * 16;
    const int l = c * QCH + ts;
    const float Dh = Dp[h];
    { // x: conv+silu, transposed store
        const int ch0 = h * HEADDIM + q4;
        float a16[16];
#pragma unroll
        for (int i = 0; i < 16; i++) a16[i] = cb[ch0 + i];
#pragma unroll
        for (int j = 0; j < 4; j++) {
            int ll = l - 3 + j;
            if (ll >= 0) {
                float xv[16];
                const ushort_t* rp = xpx + ((size_t)b * SEQ + ll) * 1024 + ch0;
                bf8_to_f(rp, xv); bf8_to_f(rp + 8, xv + 8);
#pragma unroll
                for (int i = 0; i < 16; i++) a16[i] += cw[(ch0 + i) * 4 + j] * xv[i];
            }
        }
#pragma unroll
        for (int i = 0; i < 16; i++) { float v = a16[i]; xsT[(q4 + i) * 72 + ts] = f2bfu(v * sigmoidf_(v)); }
    }
    { // B, C: plain copies from precomputed bcc
        const ushort_t* rp = bcc + ((size_t)b * SEQ + l) * 128;
        *(uint4*)&BLb[ts * 72 + q4]     = *(const uint4*)(rp + q4);
        *(uint4*)&BLb[ts * 72 + q4 + 8] = *(const uint4*)(rp + q4 + 8);
        *(uint4*)&CLb[ts * 72 + q4]     = *(const uint4*)(rp + 64 + q4);
        *(uint4*)&CLb[ts * 72 + q4 + 8] = *(const uint4*)(rp + 64 + q4 + 8);
    }
    if (tid < 64) {
        size_t gl = ((size_t)b * SEQ + c * QCH + tid) * NHEADS + h;
        float v = dalog[gl];
#pragma unroll
        for (int off = 1; off < 64; off <<= 1) {
            float u = __shfl_up(v, off, 64);
            if (tid >= off) v += u;
        }
        cum[tid] = v;
        wdt[tid] = dtv[gl];
    }
    __syncthreads();
    const int wave = tid >> 6, lane = tid & 63;
    const int quad = lane >> 4, l16 = lane & 15;
    {
        f32x4 sacc[4];
#pragma unroll
        for (int j = 0; j < 4; j++) sacc[j] = (f32x4){0.f, 0.f, 0.f, 0.f};
#pragma unroll
        for (int kk = 0; kk < 64; kk += 32) {
            bf16x8 af = *(const bf16x8*)(&CLb[(wave * 16 + l16) * 72 + kk + quad * 8]);
#pragma unroll
            for (int j = 0; j < 4; j++) {
                bf16x8 bf_ = *(const bf16x8*)(&BLb[(j * 16 + l16) * 72 + kk + quad * 8]);
                sacc[j] = __builtin_amdgcn_mfma_f32_16x16x32_bf16(af, bf_, sacc[j], 0, 0, 0);
            }
        }
#pragma unroll
        for (int r = 0; r < 4; r++) {
            const int t = wave * 16 + quad * 4 + r;
            const float ct = cum[t];
#pragma unroll
            for (int j = 0; j < 4; j++) {
                const int s = j * 16 + l16;
                float a = (s <= t) ? sacc[j][r] * __expf(ct - cum[s]) * wdt[s] : 0.f;
                attL[t * 72 + s] = f2bfu(a);
            }
        }
    }
    __syncthreads();
    {
        f32x4 accY[4], accI[4];
#pragma unroll
        for (int j = 0; j < 4; j++) { accY[j] = (f32x4){0.f, 0.f, 0.f, 0.f}; accI[j] = (f32x4){0.f, 0.f, 0.f, 0.f}; }
        const ushort_t* spg = statesT + ((size_t)(c * BATCH + b) * NHEADS + h) * (HEADDIM * DSTATE);
#pragma unroll
        for (int kk = 0; kk < 64; kk += 32) {
            bf16x8 a2 = *(const bf16x8*)(&attL[(wave * 16 + l16) * 72 + kk + quad * 8]);
            bf16x8 a3 = *(const bf16x8*)(&CLb [(wave * 16 + l16) * 72 + kk + quad * 8]);
#pragma unroll
            for (int j = 0; j < 4; j++) {
                bf16x8 b2 = *(const bf16x8*)(&xsT[(j * 16 + l16) * 72 + kk + quad * 8]);
                accY[j] = __builtin_amdgcn_mfma_f32_16x16x32_bf16(a2, b2, accY[j], 0, 0, 0);
                bf16x8 b3 = *(const bf16x8*)(spg + (j * 16 + l16) * 64 + kk + quad * 8);
                accI[j] = __builtin_amdgcn_mfma_f32_16x16x32_bf16(a3, b3, accI[j], 0, 0, 0);
            }
        }
#pragma unroll
        for (int r = 0; r < 4; r++) {
            const int t = wave * 16 + quad * 4 + r;
            const float et = __expf(cum[t]);
#pragma unroll
            for (int j = 0; j < 4; j++) {
                const int p = j * 16 + l16;
                float xv = bf2f(xsT[p * 72 + t]);
                float y = accY[j][r] + et * accI[j][r] + Dh * xv;
                BLb[t * 72 + p] = f2bfu(y);
            }
        }
    }
    __syncthreads();
    {
        ushort_t* zrow = zio + ((size_t)b * SEQ + l) * DINNER + h * HEADDIM + q4;
        float zv[16], yv[16], o[16];
        bf8_to_f(zrow, zv); bf8_to_f(zrow + 8, zv + 8);
        bf8_to_f(&BLb[ts * 72 + q4], yv); bf8_to_f(&BLb[ts * 72 + q4 + 8], yv + 8);
#pragma unroll
        for (int j = 0; j < 16; j++) {
            float z = zv[j];
            o[j] = yv[j] * z * sigmoidf_(z);
        }
        *(uint4*)(zrow)     = f8_to_bf(o);
        *(uint4*)(zrow + 8) = f8_to_bf(o + 8);
    }
}

// ---------------------------------------------------------------- RMSNorm (in place, bf16) — unchanged
__global__ void rmsnorm_k(ushort_t* yio, const float* __restrict__ nw)
{
    const int row = blockIdx.x, tid = threadIdx.x;
    uint2 u = *(const uint2*)(yio + (size_t)row * DINNER + tid * 4);
    float v0 = __uint_as_float((u.x & 0xFFFFu) << 16);
    float v1 = __uint_as_float(u.x & 0xFFFF0000u);
    float v2 = __uint_as_float((u.y & 0xFFFFu) << 16);
    float v3 = __uint_as_float(u.y & 0xFFFF0000u);
    float ss = v0 * v0 + v1 * v1 + v2 * v2 + v3 * v3;
#pragma unroll
    for (int off = 32; off >= 1; off >>= 1) ss += __shfl_xor(ss, off, 64);
    __shared__ float part[4];
    const int wave = tid >> 6;
    if ((tid & 63) == 0) part[wave] = ss;
    __syncthreads();
    float tot = part[0] + part[1] + part[2] + part[3];
    float scale = rsqrtf(tot * (1.f / DINNER) + 1e-5f);
    uint2 o;
    o.x = (uint_t)f2bfu(v0 * scale * nw[tid * 4 + 0]) | ((uint_t)f2bfu(v1 * scale * nw[tid * 4 + 1]) << 16);
    o.y = (uint_t)f2bfu(v2 * scale * nw[tid * 4 + 2]) | ((uint_t)f2bfu(v3 * scale * nw[tid * 4 + 3]) << 16);
    *(uint2*)(yio + (size_t)row * DINNER + tid * 4) = o;
}

// ---------------------------------------------------------------- launch
extern "C" void kernel_launch(void* const* d_in, const int* in_sizes, int n_in,
                              void* d_out, int out_size, void* d_ws, size_t ws_size,
                              hipStream_t stream)
{
    const float* x      = (const float*)d_in[0];
    const float* W_in   = (const float*)d_in[1];
    const float* conv_w = (const float*)d_in[2];
    const float* conv_b = (const float*)d_in[3];
    const float* dt_b   = (const float*)d_in[4];
    const float* A_log  = (const float*)d_in[5];
    const float* Dp     = (const float*)d_in[6];
    const float* nw     = (const float*)d_in[7];
    const float* W_out  = (const float*)d_in[8];
    float* out = (float*)d_out;                    // (2,4096,512) fp32

    // ---- workspace (48 MiB high-water, unchanged) ----
    char* w = (char*)d_ws;
    ushort_t* zbuf    = (ushort_t*)(w);                 // [0,16M): z -> y -> yn (in place)
    ushort_t* xpx     = (ushort_t*)(w + 16777216);      // [16M,32M): pre-conv xBC x-part
    ushort_t* statesT = (ushort_t*)(w + 33554432);      // [32M,48M): chunk states bf16 [p][n]
    ushort_t* WoutT   = (ushort_t*)(w + 33554432);      // reuses statesT region AFTER chunk_y
    // ---- d_out (16.78 MB fp32) doubles as scratch until GEMM2 overwrites it ----
    char* dscr = (char*)d_out;
    ushort_t* xpbc  = (ushort_t*)(dscr);                // [0, 2M): pre-conv B|C
    float*    dtv   = (float*)(dscr + 2097152);         // [2M, 2.5M)
    float*    dalog = (float*)(dscr + 2621440);         // [2.5M, 3M)
    float*    cdec  = (float*)(dscr + 3145728);         // [3M, 3M+8K)
    ushort_t* WinT  = (ushort_t*)(dscr + 4194304);      // [4M, 6.25M): W_in^T (dead after gemm0)
    ushort_t* bcc   = (ushort_t*)(dscr + 4194304);      // [4M, 6M): post-conv B|C (after gemm0)
    ushort_t* xb    = (ushort_t*)(dscr + 8388608);      // [8M, 16M): x bf16 (dead before gemm2)

    cast_f32_bf16_k<<<(MROWS * DMODEL / 8 + 255) / 256, 256, 0, stream>>>(x, xb, MROWS * DMODEL / 8);
    transpose_f32_bf16_k<<<dim3((NPROJ + 31) / 32, DMODEL / 32), dim3(32, 8), 0, stream>>>(W_in, WinT, DMODEL, NPROJ);
    gemm_k<0><<<dim3(18, MROWS / 128), 256, 0, stream>>>(
        xb, WinT, zbuf, xpx, xpbc, dtv, dalog, dt_b, A_log, nullptr,
        MROWS, NPROJ, DMODEL);
    // WinT dead; bcc overwrites its region
    bcconv_k<<<MROWS * 16 / 256, 256, 0, stream>>>(xpbc, conv_w, conv_b, bcc);
    chunk_state_k<<<dim3(NCHUNK, NHEADS, BATCH), 256, 0, stream>>>(
        xpx, bcc, dtv, dalog, conv_w, conv_b, statesT, cdec);
    scan_combine_k<<<BATCH * NHEADS * 4, 256, 0, stream>>>(statesT, cdec);
    chunk_y_k<<<dim3(NCHUNK, NHEADS, BATCH), 256, 0, stream>>>(
        xpx, bcc, zbuf, dtv, dalog, statesT, conv_w, conv_b, Dp);
    rmsnorm_k<<<MROWS, 256, 0, stream>>>(zbuf, nw);
    // statesT dead; transpose W_out into its region, then GEMM2
    transpose_f32_bf16_k<<<dim3(DMODEL / 32, DINNER / 32), dim3(32, 8), 0, stream>>>(W_out, WoutT, DINNER, DMODEL);
    gemm_k<1><<<dim3(4, MROWS / 128), 256, 0, stream>>>(
        zbuf, WoutT, nullptr, nullptr, nullptr, nullptr, nullptr, nullptr,
        nullptr, out, MROWS, DMODEL, DINNER);
}